// Round 1
// baseline (524.758 us; speedup 1.0000x reference)
//
#include <hip/hip_runtime.h>
#include <math.h>

// ---------------- setup kernels ----------------

__global__ void k_zero(int* __restrict__ p, int n){
  int i = blockIdx.x*256 + threadIdx.x;
  if(i < n) p[i] = 0;
}

__global__ void k_hist(const int* __restrict__ dst, int E, int* __restrict__ cnt){
  int i = blockIdx.x*256 + threadIdx.x;
  if(i < E) atomicAdd(&cnt[dst[i]], 1);
}

__global__ void k_dinv(const int* __restrict__ cnt, float* __restrict__ dinv, int n){
  int i = blockIdx.x*256 + threadIdx.x;
  if(i < n) dinv[i] = 1.0f / sqrtf((float)(cnt[i] + 1));  // +1 = self loop, deg>=1 always
}

// per-chunk (1024 elems) sums
__global__ void k_chunksum(const int* __restrict__ cnt, int* __restrict__ chunkSum, int n){
  __shared__ int sh[256];
  int base = blockIdx.x*1024;
  int s = 0;
  for(int j = threadIdx.x; j < 1024; j += 256){
    int i = base + j;
    if(i < n) s += cnt[i];
  }
  sh[threadIdx.x] = s; __syncthreads();
  for(int off = 128; off > 0; off >>= 1){
    if(threadIdx.x < off) sh[threadIdx.x] += sh[threadIdx.x + off];
    __syncthreads();
  }
  if(threadIdx.x == 0) chunkSum[blockIdx.x] = sh[0];
}

// single-block exclusive scan of chunk sums (nc <= 1024)
__global__ void k_chunkscan(const int* __restrict__ chunkSum, int* __restrict__ chunkOfs, int nc,
                            int* __restrict__ row_ofs, int N, int E){
  __shared__ int sh[1024];
  int t = threadIdx.x;
  int orig = (t < nc) ? chunkSum[t] : 0;
  sh[t] = orig; __syncthreads();
  for(int off = 1; off < 1024; off <<= 1){
    int v = (t >= off) ? sh[t - off] : 0;
    __syncthreads();
    sh[t] += v;
    __syncthreads();
  }
  if(t < nc) chunkOfs[t] = sh[t] - orig;
  if(t == 0) row_ofs[N] = E;
}

// per-chunk exclusive scan + global offset -> row_ofs, cur
__global__ void k_scanwrite(const int* __restrict__ cnt, const int* __restrict__ chunkOfs,
                            int* __restrict__ row_ofs, int* __restrict__ cur, int n){
  __shared__ int sh[256];
  int base = blockIdx.x*1024 + threadIdx.x*4;
  int v0=0,v1=0,v2=0,v3=0;
  if(base+0 < n) v0 = cnt[base+0];
  if(base+1 < n) v1 = cnt[base+1];
  if(base+2 < n) v2 = cnt[base+2];
  if(base+3 < n) v3 = cnt[base+3];
  int s = v0+v1+v2+v3;
  sh[threadIdx.x] = s; __syncthreads();
  for(int off = 1; off < 256; off <<= 1){
    int v = (threadIdx.x >= off) ? sh[threadIdx.x - off] : 0;
    __syncthreads();
    sh[threadIdx.x] += v;
    __syncthreads();
  }
  int run = chunkOfs[blockIdx.x] + sh[threadIdx.x] - s;  // exclusive prefix
  if(base+0 < n){ row_ofs[base+0] = run; cur[base+0] = run; run += v0; }
  if(base+1 < n){ row_ofs[base+1] = run; cur[base+1] = run; run += v1; }
  if(base+2 < n){ row_ofs[base+2] = run; cur[base+2] = run; run += v2; }
  if(base+3 < n){ row_ofs[base+3] = run; cur[base+3] = run; run += v3; }
}

__global__ void k_scatter(const int* __restrict__ src, const int* __restrict__ dst, int E,
                          int* __restrict__ cur, int* __restrict__ csr){
  int i = blockIdx.x*256 + threadIdx.x;
  if(i < E){
    int d = dst[i];
    int pos = atomicAdd(&cur[d], 1);
    csr[pos] = src[i];
  }
}

// ---------------- GEMM1: g1 = dinv * (x @ W1), x:[n,128], W1:[128,64] ----------------
// 64-node x 64-feat tile per block; thread tile 2 nodes x 8 feats.
// LDS reads: a = 2x ds_read_b32 (2 addrs same bank = free 2-way), b = 2x ds_read_b128 (2-way).
__global__ __launch_bounds__(256) void k_gemm1(const float* __restrict__ x, const float* __restrict__ W1,
                        const float* __restrict__ dinv, float* __restrict__ g1, int n){
  __shared__ float xs[64*128];   // 32 KB
  __shared__ float ws[128*64];   // 32 KB  -> 64 KB total, 2 blocks/CU
  int tid = threadIdx.x;
  int nodeBase = blockIdx.x*64;
  {
    const float4* w4 = (const float4*)W1;
    float4* s4 = (float4*)ws;
    for(int i = tid; i < 2048; i += 256) s4[i] = w4[i];
  }
  {
    const float4* x4 = (const float4*)x;
    float4* s4 = (float4*)xs;
    for(int i = tid; i < 2048; i += 256){
      int node = i >> 5, kg = i & 31;
      float4 v = make_float4(0.f,0.f,0.f,0.f);
      if(nodeBase + node < n) v = x4[(size_t)(nodeBase + node)*32 + kg];
      s4[i] = v;
    }
  }
  __syncthreads();
  int tx = tid & 7, ty = tid >> 3;     // tx: feat group (8 feats), ty: node pair
  int n0 = ty*2, f0 = tx*8;
  float acc[2][8];
  #pragma unroll
  for(int i = 0; i < 2; i++)
    #pragma unroll
    for(int j = 0; j < 8; j++) acc[i][j] = 0.f;

  #pragma unroll 4
  for(int k = 0; k < 128; k++){
    float a0 = xs[(n0+0)*128 + k];
    float a1 = xs[(n0+1)*128 + k];
    float4 b0 = *(const float4*)&ws[k*64 + f0];
    float4 b1 = *(const float4*)&ws[k*64 + f0 + 4];
    acc[0][0] += a0*b0.x; acc[0][1] += a0*b0.y; acc[0][2] += a0*b0.z; acc[0][3] += a0*b0.w;
    acc[0][4] += a0*b1.x; acc[0][5] += a0*b1.y; acc[0][6] += a0*b1.z; acc[0][7] += a0*b1.w;
    acc[1][0] += a1*b0.x; acc[1][1] += a1*b0.y; acc[1][2] += a1*b0.z; acc[1][3] += a1*b0.w;
    acc[1][4] += a1*b1.x; acc[1][5] += a1*b1.y; acc[1][6] += a1*b1.z; acc[1][7] += a1*b1.w;
  }
  #pragma unroll
  for(int i = 0; i < 2; i++){
    int node = nodeBase + n0 + i;
    if(node < n){
      float dv = dinv[node];
      float4 o0 = make_float4(acc[i][0]*dv, acc[i][1]*dv, acc[i][2]*dv, acc[i][3]*dv);
      float4 o1 = make_float4(acc[i][4]*dv, acc[i][5]*dv, acc[i][6]*dv, acc[i][7]*dv);
      float4* g4 = (float4*)&g1[(size_t)node*64 + f0];
      g4[0] = o0; g4[1] = o1;
    }
  }
}

// ---------------- agg1: out1 = relu(dinv[d]*(g1[d] + sum_{s in csr(d)} g1[s]) + b1) ----------------
// one wave per node, lane = feature (H=64)
__global__ __launch_bounds__(256) void k_agg1(const float* __restrict__ g1, const int* __restrict__ row_ofs,
    const int* __restrict__ csr, const float* __restrict__ dinv, const float* __restrict__ b1,
    float* __restrict__ out1, int n){
  int wid = threadIdx.x >> 6, lane = threadIdx.x & 63;
  int node = blockIdx.x*4 + wid;
  if(node >= n) return;
  int beg = row_ofs[node], end = row_ofs[node+1];
  float s = g1[(size_t)node*64 + lane];   // self loop term (dinv[d]*h[d] already folded in)
  int e = beg;
  for(; e + 4 <= end; e += 4){
    int s0 = csr[e], s1 = csr[e+1], s2 = csr[e+2], s3 = csr[e+3];
    s += g1[(size_t)s0*64 + lane];
    s += g1[(size_t)s1*64 + lane];
    s += g1[(size_t)s2*64 + lane];
    s += g1[(size_t)s3*64 + lane];
  }
  for(; e < end; e++) s += g1[(size_t)csr[e]*64 + lane];
  float v = dinv[node]*s + b1[lane];
  out1[(size_t)node*64 + lane] = fmaxf(v, 0.f);
}

// ---------------- GEMM2: g2 = dinv * (out1 @ W2), W2:[64,40] ----------------
__global__ __launch_bounds__(256) void k_gemm2(const float* __restrict__ h, const float* __restrict__ W2,
                        const float* __restrict__ dinv, float* __restrict__ g2, int n){
  __shared__ float ws[64*40];
  for(int i = threadIdx.x; i < 2560; i += 256) ws[i] = W2[i];
  __syncthreads();
  int t = blockIdx.x*256 + threadIdx.x;
  int node = t / 40, f = t - node*40;
  if(node < n){
    float s = 0.f;
    const float4* row = (const float4*)&h[(size_t)node*64];
    #pragma unroll
    for(int k4 = 0; k4 < 16; k4++){
      float4 r = row[k4];
      s += r.x*ws[(k4*4+0)*40 + f];
      s += r.y*ws[(k4*4+1)*40 + f];
      s += r.z*ws[(k4*4+2)*40 + f];
      s += r.w*ws[(k4*4+3)*40 + f];
    }
    g2[t] = dinv[node]*s;
  }
}

// ---------------- agg2 + bias + log_softmax ----------------
// one wave per node; lanes 0..39 = classes
__global__ __launch_bounds__(256) void k_agg2(const float* __restrict__ g2, const int* __restrict__ row_ofs,
     const int* __restrict__ csr, const float* __restrict__ dinv, const float* __restrict__ b2,
     float* __restrict__ out, int n){
  int wid = threadIdx.x >> 6, lane = threadIdx.x & 63;
  int node = blockIdx.x*4 + wid;
  if(node >= n) return;
  int beg = row_ofs[node], end = row_ofs[node+1];
  float s = 0.f;
  if(lane < 40) s = g2[(size_t)node*40 + lane];
  int e = beg;
  for(; e + 4 <= end; e += 4){
    int s0 = csr[e], s1 = csr[e+1], s2 = csr[e+2], s3 = csr[e+3];
    if(lane < 40){
      s += g2[(size_t)s0*40 + lane];
      s += g2[(size_t)s1*40 + lane];
      s += g2[(size_t)s2*40 + lane];
      s += g2[(size_t)s3*40 + lane];
    }
  }
  for(; e < end; e++){
    int s0 = csr[e];
    if(lane < 40) s += g2[(size_t)s0*40 + lane];
  }
  float val = -INFINITY;
  if(lane < 40) val = dinv[node]*s + b2[lane];
  // max over 40 classes (lanes >=40 hold -inf)
  float m = val;
  #pragma unroll
  for(int off = 32; off > 0; off >>= 1) m = fmaxf(m, __shfl_xor(m, off, 64));
  float ex = (lane < 40) ? expf(val - m) : 0.f;
  float l = ex;
  #pragma unroll
  for(int off = 32; off > 0; off >>= 1) l += __shfl_xor(l, off, 64);
  if(lane < 40) out[(size_t)node*40 + lane] = val - m - logf(l);
}

// ---------------- launch ----------------

extern "C" void kernel_launch(void* const* d_in, const int* in_sizes, int n_in,
                              void* d_out, int out_size, void* d_ws, size_t ws_size,
                              hipStream_t stream){
  const float* x  = (const float*)d_in[0];
  const int*   ei = (const int*)  d_in[1];
  const float* W1 = (const float*)d_in[2];
  const float* b1 = (const float*)d_in[3];
  const float* W2 = (const float*)d_in[4];
  const float* b2 = (const float*)d_in[5];
  float* out = (float*)d_out;

  int N = in_sizes[0] / 128;        // 100000
  int E = in_sizes[1] / 2;          // 1600000
  const int* src = ei;
  const int* dst = ei + E;

  // workspace carve-up (all offsets 512B-aligned)
  char* w = (char*)d_ws;
  auto alloc = [&](size_t bytes) -> char* {
    char* p = w;
    w += (bytes + 511) & ~(size_t)511;
    return p;
  };
  int*   cnt      = (int*)  alloc((size_t)N*4);
  float* dinv     = (float*)alloc((size_t)N*4);
  int*   row_ofs  = (int*)  alloc((size_t)(N+1)*4);
  int*   cur      = (int*)  alloc((size_t)N*4);
  int*   chunkSum = (int*)  alloc(1024*4);
  int*   chunkOfs = (int*)  alloc(1024*4);
  int*   csr      = (int*)  alloc((size_t)E*4);
  float* g1       = (float*)alloc((size_t)N*64*4);   // reused as g2 after agg1
  float* out1     = (float*)alloc((size_t)N*64*4);
  float* g2       = g1;

  int nchunk = (N + 1023) / 1024;

  k_zero     <<<(N+255)/256, 256, 0, stream>>>(cnt, N);
  k_hist     <<<(E+255)/256, 256, 0, stream>>>(dst, E, cnt);
  k_dinv     <<<(N+255)/256, 256, 0, stream>>>(cnt, dinv, N);
  k_chunksum <<<nchunk, 256, 0, stream>>>(cnt, chunkSum, N);
  k_chunkscan<<<1, 1024, 0, stream>>>(chunkSum, chunkOfs, nchunk, row_ofs, N, E);
  k_scanwrite<<<nchunk, 256, 0, stream>>>(cnt, chunkOfs, row_ofs, cur, N);
  k_scatter  <<<(E+255)/256, 256, 0, stream>>>(src, dst, E, cur, csr);

  k_gemm1    <<<(N+63)/64, 256, 0, stream>>>(x, W1, dinv, g1, N);
  k_agg1     <<<(N+3)/4, 256, 0, stream>>>(g1, row_ofs, csr, dinv, b1, out1, N);
  k_gemm2    <<<((size_t)N*40+255)/256, 256, 0, stream>>>(out1, W2, dinv, g2, N);
  k_agg2     <<<(N+3)/4, 256, 0, stream>>>(g2, row_ofs, csr, dinv, b2, out, N);
}